// Round 16
// baseline (133.794 us; speedup 1.0000x reference)
//
#include <hip/hip_runtime.h>
#include <hip/hip_bf16.h>

#define NF     32
#define ED     128
#define NBATCH 2048
#define NPAIRS 496
#define BM     128
#define NITER  (NBATCH / BM)   // 16 M-blocks per pair

typedef __attribute__((ext_vector_type(8))) short short8;   // 8 bf16 (MFMA A/B frag)
typedef __attribute__((ext_vector_type(4))) short short4v;  // 4 bf16
typedef __attribute__((ext_vector_type(4))) float f32x4;

#define FEMB_BF_ELEMS ((size_t)NF * NBATCH * ED)            // 8,388,608
#define WS_NEEDED     (FEMB_BF_ELEMS * 2)                   // ~16.8 MB
#define PREP_FEMB_BLOCKS 4096   // FEMB_BF_ELEMS / 8 / 256

// LDS-only barrier: orders LDS without draining the VMEM queue
// (NT stores + prefetch loads keep flowing across iterations).
#define LGKM_BARRIER() asm volatile("s_waitcnt lgkmcnt(0)\n\ts_barrier" ::: "memory")

__device__ __forceinline__ short f2bf(float x) {
    union { __hip_bfloat16 b; short s; } v;
    v.b = __float2bfloat16(x);
    return v.s;
}
__device__ __forceinline__ float bf2f(short s) {
    union { unsigned int u; float f; } v;
    v.u = ((unsigned int)(unsigned short)s) << 16;
    return v.f;
}

// ---------- Pre-pass: femb fp32 [b][f][d] -> bf16 field-major [f][b][d] ----------
__global__ __launch_bounds__(256)
void prep_femb(const float* __restrict__ femb, unsigned short* __restrict__ fb) {
    int n = blockIdx.x * 256 + threadIdx.x;       // x8 elems
    int d8 = n & 15;
    int b  = (n >> 4) & (NBATCH - 1);
    int f  = n >> 15;
    const float* s = femb + ((size_t)b * NF + f) * ED + d8 * 8;
    f32x4 lo = __builtin_nontemporal_load(reinterpret_cast<const f32x4*>(s));
    f32x4 hi = __builtin_nontemporal_load(reinterpret_cast<const f32x4*>(s + 4));
    short8 pk;
    pk[0]=f2bf(lo.x); pk[1]=f2bf(lo.y); pk[2]=f2bf(lo.z); pk[3]=f2bf(lo.w);
    pk[4]=f2bf(hi.x); pk[5]=f2bf(hi.y); pk[6]=f2bf(hi.z); pk[7]=f2bf(hi.w);
    *reinterpret_cast<short8*>(fb + ((size_t)f * NBATCH + b) * ED + d8 * 8) = pk;
}

// LDS input-tile layout: 128 rows x 256 B, byte(row,col)=row*256+(col^((row&15)<<4))
// LDS out-tile layout (epilogue, reuses ldsA): 64 rows x 512 B fp32,
//   byte(row, ebyte) = row*512 + (ebyte ^ ((row&15)<<4))

__global__ __launch_bounds__(512, 2)
void bilinear_bf16(const unsigned short* __restrict__ fb,
                   const float* __restrict__ W,
                   float* __restrict__ out)
{
    __shared__ unsigned char ldsW[128 * 256];
    __shared__ unsigned char ldsA[128 * 256];   // vi tile; reused as 64x512B out tile

    const int bid = blockIdx.x;
    const int p   = (bid & 7) * (NPAIRS / 8) + (bid >> 3);   // chunked XCD swizzle

    int fi = 0, rem = p;
    while (rem >= NF - 1 - fi) { rem -= NF - 1 - fi; ++fi; }
    const int fj = fi + 1 + rem;

    const int t    = threadIdx.x;
    const int lane = t & 63;
    const int wave = t >> 6;

    // ---- Stage W once: fp32 NT loads -> bf16 cvt -> swizzled LDS ----
    {
        const float* wp = W + (size_t)p * (ED * ED);
        #pragma unroll
        for (int it = 0; it < 4; ++it) {
            int idx8 = it * 4096 + t * 8;
            int e = idx8 >> 7, d = idx8 & 127;
            const float* s = wp + (size_t)e * ED + d;
            f32x4 lo = __builtin_nontemporal_load(reinterpret_cast<const f32x4*>(s));
            f32x4 hi = __builtin_nontemporal_load(reinterpret_cast<const f32x4*>(s + 4));
            short8 pk;
            pk[0]=f2bf(lo.x); pk[1]=f2bf(lo.y); pk[2]=f2bf(lo.z); pk[3]=f2bf(lo.w);
            pk[4]=f2bf(hi.x); pk[5]=f2bf(hi.y); pk[6]=f2bf(hi.z); pk[7]=f2bf(hi.w);
            *reinterpret_cast<short8*>(ldsW + e * 256 + ((d * 2) ^ ((e & 15) << 4))) = pk;
        }
    }

    // vi staging coords
    const int r_ = t >> 4;
    const int d_ = (t * 8) & 127;
    const unsigned short* fiPlane = fb + (size_t)fi * NBATCH * ED;
    const unsigned short* fjPlane = fb + (size_t)fj * NBATCH * ED;

    const int we  = wave & 3;       // e-quadrant
    const int wb_ = wave >> 2;      // b-half
    const int lhi = lane >> 4;
    const int llo = lane & 15;

    // Epilogue read-role coords (fixed per thread): rows row_, row_+2, +4, +6
    const int row_ = wave * 8 + (lane >> 5);   // 0..63 step pattern
    const int e0_  = (lane & 31) * 4;          // 0..124

    short8 stg[4];
    #pragma unroll
    for (int q = 0; q < 4; ++q)
        stg[q] = *reinterpret_cast<const short8*>(fiPlane + (size_t)(r_ + q * 32) * ED + d_);

    for (int mb = 0; mb < NITER; ++mb) {
        const int b0 = mb * BM;

        // ---- A-write: staged bf16 -> swizzled LDS ----
        #pragma unroll
        for (int q = 0; q < 4; ++q) {
            int r = r_ + q * 32;
            *reinterpret_cast<short8*>(ldsA + r * 256 + ((d_ * 2) ^ ((r & 15) << 4))) = stg[q];
        }
        LGKM_BARRIER();

        // ---- Issue next vi prefetch ----
        if (mb + 1 < NITER) {
            const unsigned short* base = fiPlane + (size_t)((mb + 1) * BM + r_) * ED + d_;
            #pragma unroll
            for (int q = 0; q < 4; ++q)
                stg[q] = *reinterpret_cast<const short8*>(base + (size_t)q * 32 * ED);
        }

        // ---- T14 issue-early: vj for h=0 pass (hidden under MFMA cluster) ----
        short4v vj0[4];
        #pragma unroll
        for (int s = 0; s < 4; ++s) {
            int b = b0 + row_ + s * 2;                     // h=0 rows
            vj0[s] = *reinterpret_cast<const short4v*>(fjPlane + (size_t)b * ED + e0_);
        }

        // ---- Compute: D[e][b] = W . vi^T ----
        f32x4 acc[2][4] = {};
        #pragma unroll
        for (int kk = 0; kk < 4; ++kk) {
            const int db = kk * 64 + lhi * 16;
            short8 a[2], b[4];
            #pragma unroll
            for (int mi = 0; mi < 2; ++mi) {
                int e = we * 32 + mi * 16 + llo;
                a[mi] = *reinterpret_cast<const short8*>(ldsW + e * 256 + (db ^ (llo << 4)));
            }
            #pragma unroll
            for (int ni = 0; ni < 4; ++ni) {
                int r = wb_ * 64 + ni * 16 + llo;
                b[ni] = *reinterpret_cast<const short8*>(ldsA + r * 256 + (db ^ (llo << 4)));
            }
            #pragma unroll
            for (int mi = 0; mi < 2; ++mi)
                #pragma unroll
                for (int ni = 0; ni < 4; ++ni)
                    acc[mi][ni] = __builtin_amdgcn_mfma_f32_16x16x32_bf16(a[mi], b[ni], acc[mi][ni], 0, 0, 0);
        }
        LGKM_BARRIER();   // all MFMA ldsA reads done -> safe to reuse as out tile

        // ---- T14 issue-early: vj for h=1 pass (hidden under h=0 pass) ----
        short4v vj1[4];
        #pragma unroll
        for (int s = 0; s < 4; ++s) {
            int b = b0 + 64 + row_ + s * 2;                // h=1 rows
            vj1[s] = *reinterpret_cast<const short4v*>(fjPlane + (size_t)b * ED + e0_);
        }

        // ---- Epilogue: LDS-transpose -> CONTIGUOUS 512B-segment NT stores ----
        #pragma unroll
        for (int h = 0; h < 2; ++h) {
            if (wb_ == h) {
                #pragma unroll
                for (int ni = 0; ni < 4; ++ni) {
                    int row = ni * 16 + llo;                       // 0..63
                    #pragma unroll
                    for (int mi = 0; mi < 2; ++mi) {
                        int ebyte = (we * 32 + mi * 16 + lhi * 4) * 4;
                        int byte  = row * 512 + (ebyte ^ ((row & 15) << 4));
                        *reinterpret_cast<f32x4*>(ldsA + byte) = acc[mi][ni];
                    }
                }
            }
            LGKM_BARRIER();   // out-tile half visible to all waves
            #pragma unroll
            for (int s = 0; s < 4; ++s) {
                int row  = row_ + s * 2;                            // 0..63
                int byte = row * 512 + ((e0_ * 4) ^ ((row & 15) << 4));
                f32x4 r = *reinterpret_cast<const f32x4*>(ldsA + byte);
                int b = b0 + h * 64 + row;
                short4v vs = (h == 0) ? vj0[s] : vj1[s];
                f32x4 o;
                o.x = r.x * bf2f(vs[0]); o.y = r.y * bf2f(vs[1]);
                o.z = r.z * bf2f(vs[2]); o.w = r.w * bf2f(vs[3]);
                float* op = out + ((size_t)b * NPAIRS + p) * ED + e0_;
                __builtin_nontemporal_store(o, reinterpret_cast<f32x4*>(op));
            }
            LGKM_BARRIER();   // reads done -> next write (h=1 or next A-write) safe
        }
    }
}

// ---------- Fallback (fp32 inputs) if ws too small ----------
__global__ __launch_bounds__(512, 2)
void bilinear_f32(const float* __restrict__ femb,
                  const float* __restrict__ W,
                  float* __restrict__ out)
{
    __shared__ unsigned char ldsW[128 * 256];
    __shared__ unsigned char ldsA[128 * 256];

    const int p = blockIdx.x;
    int fi = 0, rem = p;
    while (rem >= NF - 1 - fi) { rem -= NF - 1 - fi; ++fi; }
    const int fj = fi + 1 + rem;

    const int t    = threadIdx.x;
    const int lane = t & 63;
    const int wave = t >> 6;

    {
        const float* wp = W + (size_t)p * (ED * ED);
        #pragma unroll
        for (int it = 0; it < 4; ++it) {
            int idx8 = it * 4096 + t * 8;
            int e = idx8 >> 7, d = idx8 & 127;
            const float* s = wp + (size_t)e * ED + d;
            f32x4 lo = __builtin_nontemporal_load(reinterpret_cast<const f32x4*>(s));
            f32x4 hi = __builtin_nontemporal_load(reinterpret_cast<const f32x4*>(s + 4));
            short8 pk;
            pk[0]=f2bf(lo.x); pk[1]=f2bf(lo.y); pk[2]=f2bf(lo.z); pk[3]=f2bf(lo.w);
            pk[4]=f2bf(hi.x); pk[5]=f2bf(hi.y); pk[6]=f2bf(hi.z); pk[7]=f2bf(hi.w);
            *reinterpret_cast<short8*>(ldsW + e * 256 + ((d * 2) ^ ((e & 15) << 4))) = pk;
        }
    }

    const int r_ = t >> 4;
    const int d_ = (t * 8) & 127;
    const size_t ROWSTRIDE32 = (size_t)32 * NF * ED;

    const int we  = wave & 3;
    const int wb_ = wave >> 2;
    const int lhi = lane >> 4;
    const int llo = lane & 15;

    f32x4 stg[8];
    {
        const float* base = femb + ((size_t)r_ * NF + fi) * ED + d_;
        #pragma unroll
        for (int q = 0; q < 4; ++q) {
            const float* s = base + (size_t)q * ROWSTRIDE32;
            stg[2*q]   = *reinterpret_cast<const f32x4*>(s);
            stg[2*q+1] = *reinterpret_cast<const f32x4*>(s + 4);
        }
    }

    for (int mb = 0; mb < NITER; ++mb) {
        const int b0 = mb * BM;
        #pragma unroll
        for (int q = 0; q < 4; ++q) {
            int r = r_ + q * 32;
            f32x4 lo = stg[2*q], hi = stg[2*q+1];
            short8 pk;
            pk[0]=f2bf(lo.x); pk[1]=f2bf(lo.y); pk[2]=f2bf(lo.z); pk[3]=f2bf(lo.w);
            pk[4]=f2bf(hi.x); pk[5]=f2bf(hi.y); pk[6]=f2bf(hi.z); pk[7]=f2bf(hi.w);
            *reinterpret_cast<short8*>(ldsA + r * 256 + ((d_ * 2) ^ ((r & 15) << 4))) = pk;
        }
        __syncthreads();

        if (mb + 1 < NITER) {
            const float* base = femb + ((size_t)((mb + 1) * BM + r_) * NF + fi) * ED + d_;
            #pragma unroll
            for (int q = 0; q < 4; ++q) {
                const float* s = base + (size_t)q * ROWSTRIDE32;
                stg[2*q]   = *reinterpret_cast<const f32x4*>(s);
                stg[2*q+1] = *reinterpret_cast<const f32x4*>(s + 4);
            }
        }

        f32x4 vjr[4][2];
        #pragma unroll
        for (int ni = 0; ni < 4; ++ni) {
            int b = b0 + wb_ * 64 + ni * 16 + llo;
            const float* vj = femb + ((size_t)b * NF + fj) * ED;
            #pragma unroll
            for (int mi = 0; mi < 2; ++mi) {
                int e0 = we * 32 + mi * 16 + lhi * 4;
                vjr[ni][mi] = *reinterpret_cast<const f32x4*>(vj + e0);
            }
        }

        f32x4 acc[2][4] = {};
        #pragma unroll
        for (int kk = 0; kk < 4; ++kk) {
            const int db = kk * 64 + lhi * 16;
            short8 a[2], b[4];
            #pragma unroll
            for (int mi = 0; mi < 2; ++mi) {
                int e = we * 32 + mi * 16 + llo;
                a[mi] = *reinterpret_cast<const short8*>(ldsW + e * 256 + (db ^ (llo << 4)));
            }
            #pragma unroll
            for (int ni = 0; ni < 4; ++ni) {
                int r = wb_ * 64 + ni * 16 + llo;
                b[ni] = *reinterpret_cast<const short8*>(ldsA + r * 256 + (db ^ (llo << 4)));
            }
            #pragma unroll
            for (int mi = 0; mi < 2; ++mi)
                #pragma unroll
                for (int ni = 0; ni < 4; ++ni)
                    acc[mi][ni] = __builtin_amdgcn_mfma_f32_16x16x32_bf16(a[mi], b[ni], acc[mi][ni], 0, 0, 0);
        }
        __syncthreads();

        #pragma unroll
        for (int ni = 0; ni < 4; ++ni) {
            int b = b0 + wb_ * 64 + ni * 16 + llo;
            float* op = out + ((size_t)b * NPAIRS + p) * ED;
            #pragma unroll
            for (int mi = 0; mi < 2; ++mi) {
                int e0 = we * 32 + mi * 16 + lhi * 4;
                f32x4 v = vjr[ni][mi];
                f32x4 r = acc[mi][ni];
                f32x4 o;
                o.x = r[0] * v.x; o.y = r[1] * v.y;
                o.z = r[2] * v.z; o.w = r[3] * v.w;
                __builtin_nontemporal_store(o, reinterpret_cast<f32x4*>(op + e0));
            }
        }
    }
}

extern "C" void kernel_launch(void* const* d_in, const int* in_sizes, int n_in,
                              void* d_out, int out_size, void* d_ws, size_t ws_size,
                              hipStream_t stream) {
    (void)in_sizes; (void)n_in; (void)out_size;
    const float* femb = (const float*)d_in[0];
    const float* W    = (const float*)d_in[1];
    float* out        = (float*)d_out;

    if (ws_size >= WS_NEEDED) {
        unsigned short* fbp = (unsigned short*)d_ws;
        hipLaunchKernelGGL(prep_femb, dim3(PREP_FEMB_BLOCKS), dim3(256), 0, stream, femb, fbp);
        hipLaunchKernelGGL(bilinear_bf16, dim3(NPAIRS), dim3(512), 0, stream, fbp, W, out);
    } else {
        hipLaunchKernelGGL(bilinear_f32, dim3(NPAIRS), dim3(512), 0, stream, femb, W, out);
    }
}

// Round 17
// 123.864 us; speedup vs baseline: 1.0802x; 1.0802x over previous
//
#include <hip/hip_runtime.h>
#include <hip/hip_bf16.h>

#define NF     32
#define ED     128
#define NBATCH 2048
#define NPAIRS 496
#define BM     128
#define NITER  (NBATCH / BM)   // 16 M-blocks per pair

typedef __attribute__((ext_vector_type(8))) short short8;   // 8 bf16 (MFMA A/B frag)
typedef __attribute__((ext_vector_type(4))) short short4v;  // 4 bf16
typedef __attribute__((ext_vector_type(4))) float f32x4;

#define FEMB_BF_ELEMS ((size_t)NF * NBATCH * ED)            // 8,388,608
#define WS_NEEDED     (FEMB_BF_ELEMS * 2)                   // ~16.8 MB
#define PREP_FEMB_BLOCKS 4096   // FEMB_BF_ELEMS / 8 / 256

// LDS-only barrier: orders LDS without draining the VMEM queue
// (NT stores + prefetch loads keep flowing across iterations).
#define LGKM_BARRIER() asm volatile("s_waitcnt lgkmcnt(0)\n\ts_barrier" ::: "memory")

__device__ __forceinline__ short f2bf(float x) {
    union { __hip_bfloat16 b; short s; } v;
    v.b = __float2bfloat16(x);
    return v.s;
}
__device__ __forceinline__ float bf2f(short s) {
    union { unsigned int u; float f; } v;
    v.u = ((unsigned int)(unsigned short)s) << 16;
    return v.f;
}

// ---------- Pre-pass: femb fp32 [b][f][d] -> bf16 field-major [f][b][d] ----------
__global__ __launch_bounds__(256)
void prep_femb(const float* __restrict__ femb, unsigned short* __restrict__ fb) {
    int n = blockIdx.x * 256 + threadIdx.x;       // x8 elems
    int d8 = n & 15;
    int b  = (n >> 4) & (NBATCH - 1);
    int f  = n >> 15;
    const float* s = femb + ((size_t)b * NF + f) * ED + d8 * 8;
    f32x4 lo = __builtin_nontemporal_load(reinterpret_cast<const f32x4*>(s));
    f32x4 hi = __builtin_nontemporal_load(reinterpret_cast<const f32x4*>(s + 4));
    short8 pk;
    pk[0]=f2bf(lo.x); pk[1]=f2bf(lo.y); pk[2]=f2bf(lo.z); pk[3]=f2bf(lo.w);
    pk[4]=f2bf(hi.x); pk[5]=f2bf(hi.y); pk[6]=f2bf(hi.z); pk[7]=f2bf(hi.w);
    *reinterpret_cast<short8*>(fb + ((size_t)f * NBATCH + b) * ED + d8 * 8) = pk;
}

// LDS input-tile layout: 128 rows x 256 B, byte(row,col)=row*256+(col^((row&15)<<4))
// LDS out-tile layout (epilogue, reuses ldsA): 64 rows x 512 B fp32,
//   byte(row, ebyte) = row*512 + (ebyte ^ ((row&15)<<4))

__global__ __launch_bounds__(512, 2)
void bilinear_bf16(const unsigned short* __restrict__ fb,
                   const float* __restrict__ W,
                   float* __restrict__ out)
{
    __shared__ unsigned char ldsW[128 * 256];
    __shared__ unsigned char ldsA[128 * 256];   // vi tile; reused as 64x512B out tile

    const int bid = blockIdx.x;
    const int p   = (bid & 7) * (NPAIRS / 8) + (bid >> 3);   // chunked XCD swizzle

    int fi = 0, rem = p;
    while (rem >= NF - 1 - fi) { rem -= NF - 1 - fi; ++fi; }
    const int fj = fi + 1 + rem;

    const int t    = threadIdx.x;
    const int lane = t & 63;
    const int wave = t >> 6;

    // ---- Stage W once: fp32 NT loads -> bf16 cvt -> swizzled LDS ----
    {
        const float* wp = W + (size_t)p * (ED * ED);
        #pragma unroll
        for (int it = 0; it < 4; ++it) {
            int idx8 = it * 4096 + t * 8;
            int e = idx8 >> 7, d = idx8 & 127;
            const float* s = wp + (size_t)e * ED + d;
            f32x4 lo = __builtin_nontemporal_load(reinterpret_cast<const f32x4*>(s));
            f32x4 hi = __builtin_nontemporal_load(reinterpret_cast<const f32x4*>(s + 4));
            short8 pk;
            pk[0]=f2bf(lo.x); pk[1]=f2bf(lo.y); pk[2]=f2bf(lo.z); pk[3]=f2bf(lo.w);
            pk[4]=f2bf(hi.x); pk[5]=f2bf(hi.y); pk[6]=f2bf(hi.z); pk[7]=f2bf(hi.w);
            *reinterpret_cast<short8*>(ldsW + e * 256 + ((d * 2) ^ ((e & 15) << 4))) = pk;
        }
    }

    // vi staging coords
    const int r_ = t >> 4;
    const int d_ = (t * 8) & 127;
    const unsigned short* fiPlane = fb + (size_t)fi * NBATCH * ED;
    const unsigned short* fjPlane = fb + (size_t)fj * NBATCH * ED;

    const int we  = wave & 3;       // e-quadrant
    const int wb_ = wave >> 2;      // b-half
    const int lhi = lane >> 4;
    const int llo = lane & 15;

    short8 stg[4];
    #pragma unroll
    for (int q = 0; q < 4; ++q)
        stg[q] = *reinterpret_cast<const short8*>(fiPlane + (size_t)(r_ + q * 32) * ED + d_);

    for (int mb = 0; mb < NITER; ++mb) {
        const int b0 = mb * BM;

        // ---- A-write: staged bf16 -> swizzled LDS ----
        #pragma unroll
        for (int q = 0; q < 4; ++q) {
            int r = r_ + q * 32;
            *reinterpret_cast<short8*>(ldsA + r * 256 + ((d_ * 2) ^ ((r & 15) << 4))) = stg[q];
        }
        LGKM_BARRIER();

        // ---- Issue next vi prefetch ----
        if (mb + 1 < NITER) {
            const unsigned short* base = fiPlane + (size_t)((mb + 1) * BM + r_) * ED + d_;
            #pragma unroll
            for (int q = 0; q < 4; ++q)
                stg[q] = *reinterpret_cast<const short8*>(base + (size_t)q * 32 * ED);
        }

        // ---- Compute: D[e][b] = W . vi^T ----
        f32x4 acc[2][4] = {};
        #pragma unroll
        for (int kk = 0; kk < 4; ++kk) {
            const int db = kk * 64 + lhi * 16;
            short8 a[2], b[4];
            #pragma unroll
            for (int mi = 0; mi < 2; ++mi) {
                int e = we * 32 + mi * 16 + llo;
                a[mi] = *reinterpret_cast<const short8*>(ldsW + e * 256 + (db ^ (llo << 4)));
            }
            #pragma unroll
            for (int ni = 0; ni < 4; ++ni) {
                int r = wb_ * 64 + ni * 16 + llo;
                b[ni] = *reinterpret_cast<const short8*>(ldsA + r * 256 + (db ^ (llo << 4)));
            }
            #pragma unroll
            for (int mi = 0; mi < 2; ++mi)
                #pragma unroll
                for (int ni = 0; ni < 4; ++ni)
                    acc[mi][ni] = __builtin_amdgcn_mfma_f32_16x16x32_bf16(a[mi], b[ni], acc[mi][ni], 0, 0, 0);
        }
        LGKM_BARRIER();   // all MFMA ldsA reads done -> safe to reuse as out tile

        // ---- Epilogue: LDS-transpose -> CONTIGUOUS 512B-segment NT stores ----
        // Pass h: waves with wb_==h write their acc quadrants into a 64x512B
        // fp32 tile (rows = b-local), then ALL waves read whole rows and store
        // out[b][p][0..127] as 512B-contiguous segments (2 rows per instr).
        #pragma unroll
        for (int h = 0; h < 2; ++h) {
            if (wb_ == h) {
                #pragma unroll
                for (int ni = 0; ni < 4; ++ni) {
                    int row = ni * 16 + llo;                       // 0..63
                    #pragma unroll
                    for (int mi = 0; mi < 2; ++mi) {
                        int ebyte = (we * 32 + mi * 16 + lhi * 4) * 4;
                        int byte  = row * 512 + (ebyte ^ ((row & 15) << 4));
                        *reinterpret_cast<f32x4*>(ldsA + byte) = acc[mi][ni];
                    }
                }
            }
            LGKM_BARRIER();   // out-tile half visible to all waves
            #pragma unroll
            for (int s = 0; s < 4; ++s) {
                int row  = wave * 8 + s * 2 + (lane >> 5);          // 0..63
                int e0   = (lane & 31) * 4;                         // 0..124
                int byte = row * 512 + ((e0 * 4) ^ ((row & 15) << 4));
                f32x4 r = *reinterpret_cast<const f32x4*>(ldsA + byte);
                int b = b0 + h * 64 + row;
                short4v vs = *reinterpret_cast<const short4v*>(
                    fjPlane + (size_t)b * ED + e0);                 // contiguous 8B/lane
                f32x4 o;
                o.x = r.x * bf2f(vs[0]); o.y = r.y * bf2f(vs[1]);
                o.z = r.z * bf2f(vs[2]); o.w = r.w * bf2f(vs[3]);
                float* op = out + ((size_t)b * NPAIRS + p) * ED + e0;
                __builtin_nontemporal_store(o, reinterpret_cast<f32x4*>(op));
            }
            LGKM_BARRIER();   // reads done -> next write (h=1 or next A-write) safe
        }
    }
}

// ---------- Fallback (fp32 inputs) if ws too small ----------
__global__ __launch_bounds__(512, 2)
void bilinear_f32(const float* __restrict__ femb,
                  const float* __restrict__ W,
                  float* __restrict__ out)
{
    __shared__ unsigned char ldsW[128 * 256];
    __shared__ unsigned char ldsA[128 * 256];

    const int p = blockIdx.x;
    int fi = 0, rem = p;
    while (rem >= NF - 1 - fi) { rem -= NF - 1 - fi; ++fi; }
    const int fj = fi + 1 + rem;

    const int t    = threadIdx.x;
    const int lane = t & 63;
    const int wave = t >> 6;

    {
        const float* wp = W + (size_t)p * (ED * ED);
        #pragma unroll
        for (int it = 0; it < 4; ++it) {
            int idx8 = it * 4096 + t * 8;
            int e = idx8 >> 7, d = idx8 & 127;
            const float* s = wp + (size_t)e * ED + d;
            f32x4 lo = __builtin_nontemporal_load(reinterpret_cast<const f32x4*>(s));
            f32x4 hi = __builtin_nontemporal_load(reinterpret_cast<const f32x4*>(s + 4));
            short8 pk;
            pk[0]=f2bf(lo.x); pk[1]=f2bf(lo.y); pk[2]=f2bf(lo.z); pk[3]=f2bf(lo.w);
            pk[4]=f2bf(hi.x); pk[5]=f2bf(hi.y); pk[6]=f2bf(hi.z); pk[7]=f2bf(hi.w);
            *reinterpret_cast<short8*>(ldsW + e * 256 + ((d * 2) ^ ((e & 15) << 4))) = pk;
        }
    }

    const int r_ = t >> 4;
    const int d_ = (t * 8) & 127;
    const size_t ROWSTRIDE32 = (size_t)32 * NF * ED;

    const int we  = wave & 3;
    const int wb_ = wave >> 2;
    const int lhi = lane >> 4;
    const int llo = lane & 15;

    f32x4 stg[8];
    {
        const float* base = femb + ((size_t)r_ * NF + fi) * ED + d_;
        #pragma unroll
        for (int q = 0; q < 4; ++q) {
            const float* s = base + (size_t)q * ROWSTRIDE32;
            stg[2*q]   = *reinterpret_cast<const f32x4*>(s);
            stg[2*q+1] = *reinterpret_cast<const f32x4*>(s + 4);
        }
    }

    for (int mb = 0; mb < NITER; ++mb) {
        const int b0 = mb * BM;
        #pragma unroll
        for (int q = 0; q < 4; ++q) {
            int r = r_ + q * 32;
            f32x4 lo = stg[2*q], hi = stg[2*q+1];
            short8 pk;
            pk[0]=f2bf(lo.x); pk[1]=f2bf(lo.y); pk[2]=f2bf(lo.z); pk[3]=f2bf(lo.w);
            pk[4]=f2bf(hi.x); pk[5]=f2bf(hi.y); pk[6]=f2bf(hi.z); pk[7]=f2bf(hi.w);
            *reinterpret_cast<short8*>(ldsA + r * 256 + ((d_ * 2) ^ ((r & 15) << 4))) = pk;
        }
        __syncthreads();

        if (mb + 1 < NITER) {
            const float* base = femb + ((size_t)((mb + 1) * BM + r_) * NF + fi) * ED + d_;
            #pragma unroll
            for (int q = 0; q < 4; ++q) {
                const float* s = base + (size_t)q * ROWSTRIDE32;
                stg[2*q]   = *reinterpret_cast<const f32x4*>(s);
                stg[2*q+1] = *reinterpret_cast<const f32x4*>(s + 4);
            }
        }

        f32x4 vjr[4][2];
        #pragma unroll
        for (int ni = 0; ni < 4; ++ni) {
            int b = b0 + wb_ * 64 + ni * 16 + llo;
            const float* vj = femb + ((size_t)b * NF + fj) * ED;
            #pragma unroll
            for (int mi = 0; mi < 2; ++mi) {
                int e0 = we * 32 + mi * 16 + lhi * 4;
                vjr[ni][mi] = *reinterpret_cast<const f32x4*>(vj + e0);
            }
        }

        f32x4 acc[2][4] = {};
        #pragma unroll
        for (int kk = 0; kk < 4; ++kk) {
            const int db = kk * 64 + lhi * 16;
            short8 a[2], b[4];
            #pragma unroll
            for (int mi = 0; mi < 2; ++mi) {
                int e = we * 32 + mi * 16 + llo;
                a[mi] = *reinterpret_cast<const short8*>(ldsW + e * 256 + (db ^ (llo << 4)));
            }
            #pragma unroll
            for (int ni = 0; ni < 4; ++ni) {
                int r = wb_ * 64 + ni * 16 + llo;
                b[ni] = *reinterpret_cast<const short8*>(ldsA + r * 256 + (db ^ (llo << 4)));
            }
            #pragma unroll
            for (int mi = 0; mi < 2; ++mi)
                #pragma unroll
                for (int ni = 0; ni < 4; ++ni)
                    acc[mi][ni] = __builtin_amdgcn_mfma_f32_16x16x32_bf16(a[mi], b[ni], acc[mi][ni], 0, 0, 0);
        }
        __syncthreads();

        #pragma unroll
        for (int ni = 0; ni < 4; ++ni) {
            int b = b0 + wb_ * 64 + ni * 16 + llo;
            float* op = out + ((size_t)b * NPAIRS + p) * ED;
            #pragma unroll
            for (int mi = 0; mi < 2; ++mi) {
                int e0 = we * 32 + mi * 16 + lhi * 4;
                f32x4 v = vjr[ni][mi];
                f32x4 r = acc[mi][ni];
                f32x4 o;
                o.x = r[0] * v.x; o.y = r[1] * v.y;
                o.z = r[2] * v.z; o.w = r[3] * v.w;
                __builtin_nontemporal_store(o, reinterpret_cast<f32x4*>(op + e0));
            }
        }
    }
}

extern "C" void kernel_launch(void* const* d_in, const int* in_sizes, int n_in,
                              void* d_out, int out_size, void* d_ws, size_t ws_size,
                              hipStream_t stream) {
    (void)in_sizes; (void)n_in; (void)out_size;
    const float* femb = (const float*)d_in[0];
    const float* W    = (const float*)d_in[1];
    float* out        = (float*)d_out;

    if (ws_size >= WS_NEEDED) {
        unsigned short* fbp = (unsigned short*)d_ws;
        hipLaunchKernelGGL(prep_femb, dim3(PREP_FEMB_BLOCKS), dim3(256), 0, stream, femb, fbp);
        hipLaunchKernelGGL(bilinear_bf16, dim3(NPAIRS), dim3(512), 0, stream, fbp, W, out);
    } else {
        hipLaunchKernelGGL(bilinear_f32, dim3(NPAIRS), dim3(512), 0, stream, femb, W, out);
    }
}